// Round 1
// baseline (1118.623 us; speedup 1.0000x reference)
//
#include <hip/hip_runtime.h>

#define LN_EPS 1e-5f

// B=32768, F=64, D=128, all fp32.
// out[bt,i,d] = LN_d( x[bt,i]*W[i,d] + b[i,d] ) * gamma[d] + beta[d]
//
// Mapping: each 32-lane half-wave owns one output row (128 floats, 4/lane as
// float4). Each wave pins one feature PAIR (i, i+1) for the entire kernel so
// W/b/gamma/beta fragments live in registers; a wave's two half-rows are
// adjacent in memory -> each float4 store is 1 KiB fully contiguous per wave.
// Grid-stride over batches. 2048 blocks x 256 thr = 8192 waves = 32 waves/CU.

__global__ __launch_bounds__(256) void tabemb_ln_kernel(
    const float* __restrict__ x,     // [32768, 64]
    const float* __restrict__ W,     // [64, 128]
    const float* __restrict__ b,     // [64, 128]
    const float* __restrict__ gamma, // [128]
    const float* __restrict__ beta,  // [128]
    float* __restrict__ out,         // [32768, 64, 128]
    int batch)
{
    const int gw   = (blockIdx.x << 2) + (threadIdx.x >> 6); // global wave 0..8191
    const int lane = threadIdx.x & 63;
    const int half = lane >> 5;             // which row of the pair
    const int l    = lane & 31;             // lane within row
    const int fp   = gw & 31;               // feature pair 0..31
    const int i    = (fp << 1) + half;      // feature index 0..63
    const int d0   = l << 2;                // embed start 0..124

    // Register-resident per-wave constants
    const float4 w4  = *(const float4*)(W     + (i << 7) + d0);
    const float4 b4  = *(const float4*)(b     + (i << 7) + d0);
    const float4 g4  = *(const float4*)(gamma + d0);
    const float4 be4 = *(const float4*)(beta  + d0);

    const int    bstart  = gw >> 5;         // 0..255
    const int    bstride = 256;             // (8192 waves)/(32 pairs)
    const size_t rowoff  = ((size_t)i << 7) + (size_t)d0;

    for (int bt = bstart; bt < batch; bt += bstride) {
        const float xv = x[(bt << 6) + i];  // same addr across half-wave -> HW broadcast

        float4 e;
        e.x = fmaf(xv, w4.x, b4.x);
        e.y = fmaf(xv, w4.y, b4.y);
        e.z = fmaf(xv, w4.z, b4.z);
        e.w = fmaf(xv, w4.w, b4.w);

        float s  = e.x + e.y + e.z + e.w;
        float s2 = fmaf(e.x, e.x, fmaf(e.y, e.y, fmaf(e.z, e.z, e.w * e.w)));

        // 32-lane butterfly (masks <32 never cross the half-wave boundary)
        #pragma unroll
        for (int m = 1; m <= 16; m <<= 1) {
            s  += __shfl_xor(s,  m, 64);
            s2 += __shfl_xor(s2, m, 64);
        }

        const float mean = s * 0.0078125f;                       // /128
        const float var  = fmaf(-mean, mean, s2 * 0.0078125f);   // E[e^2]-mean^2
        const float inv  = rsqrtf(var + LN_EPS);

        float4 o; float c1, c0;
        c1 = inv * g4.x; c0 = fmaf(-mean, c1, be4.x); o.x = fmaf(e.x, c1, c0);
        c1 = inv * g4.y; c0 = fmaf(-mean, c1, be4.y); o.y = fmaf(e.y, c1, c0);
        c1 = inv * g4.z; c0 = fmaf(-mean, c1, be4.z); o.z = fmaf(e.z, c1, c0);
        c1 = inv * g4.w; c0 = fmaf(-mean, c1, be4.w); o.w = fmaf(e.w, c1, c0);

        *(float4*)(out + (size_t)bt * 8192 + rowoff) = o;
    }
}

extern "C" void kernel_launch(void* const* d_in, const int* in_sizes, int n_in,
                              void* d_out, int out_size, void* d_ws, size_t ws_size,
                              hipStream_t stream) {
    const float* x     = (const float*)d_in[0];
    const float* W     = (const float*)d_in[1];
    const float* b     = (const float*)d_in[2];
    const float* gamma = (const float*)d_in[3];
    const float* beta  = (const float*)d_in[4];
    float* out = (float*)d_out;

    const int batch = in_sizes[0] / 64;  // 32768

    tabemb_ln_kernel<<<2048, 256, 0, stream>>>(x, W, b, gamma, beta, out, batch);
}